// Round 1
// baseline (699.789 us; speedup 1.0000x reference)
//
#include <hip/hip_runtime.h>
#include <hip/hip_bf16.h>

// Problem constants
#define B_   2
#define C_   64
#define H_   96
#define W_   192
#define D_   48
#define G_   8
#define GC_  8
#define OUT_ 32
#define HW_  (H_ * W_)   // 18432

// Workspace layout (float offsets)
//  fln  : (B,G,H,W,8)    [0,        2359296)
//  frn  : (B,G,H,W,8)    [2359296,  4718592)
//  base : (B,D,H,W,G)    [4718592, 18874368)
//  sw   : (B,H,W,3)      [18874368,18984960)
//  wT   : (3,27,8gi,8g)  [18984960,18990144)
//  wp1T : (65,9,32oc)    [18990144,19008864)
#define OFF_FLN  0
#define OFF_FRN  2359296
#define OFF_BASE 4718592
#define OFF_SW   18874368
#define OFF_WT   18984960
#define OFF_WP1T 18990144

// ---------------------------------------------------------------------------
// Kernel 0: weight transposes (tap-major / oc-contiguous for uniform s_loads)
// ---------------------------------------------------------------------------
__global__ void wtrans_kernel(const float* __restrict__ w_s,
                              const float* __restrict__ w_m,
                              const float* __restrict__ w_l,
                              const float* __restrict__ w_pred1,
                              float* __restrict__ wT,
                              float* __restrict__ wp1T) {
    int i = blockIdx.x * 256 + threadIdx.x;
    if (i < 5184) {
        // wT[k][tap][gi][g] = w_k[g][gi][tap]
        int k = i / 1728; int r = i - k * 1728;
        int tap = r >> 6; int q = r & 63; int gi = q >> 3; int g = q & 7;
        const float* src = (k == 0) ? w_s : (k == 1) ? w_m : w_l;
        wT[i] = src[(g * 8 + gi) * 27 + tap];
    } else if (i < 5184 + 18720) {
        // wp1T[ic][t][oc] = w_pred1[oc][ic][t]
        int j = i - 5184;
        int oc = j & 31; int it = j >> 5; int ic = it / 9; int t = it - ic * 9;
        wp1T[j] = w_pred1[(oc * 65 + ic) * 9 + t];
    }
}

// ---------------------------------------------------------------------------
// Kernel 1: group-L2-normalize + transpose to channel-last (B,G,H,W,8)
// ---------------------------------------------------------------------------
__global__ __launch_bounds__(256) void norm_kernel(const float* __restrict__ feat_l,
                                                   const float* __restrict__ feat_r,
                                                   float* __restrict__ fln,
                                                   float* __restrict__ frn) {
    int hw = blockIdx.x * 256 + threadIdx.x;   // 0..18431
    int bg = blockIdx.y;                       // 0..15  (b*G+g)
    const float* src = blockIdx.z ? feat_r : feat_l;
    float*       dst = blockIdx.z ? frn    : fln;
    float v[8]; float s = 0.f;
    #pragma unroll
    for (int c = 0; c < 8; ++c) {
        v[c] = src[(bg * 8 + c) * HW_ + hw];
        s += v[c] * v[c];
    }
    float n = fmaxf(sqrtf(s), 1e-12f);
    float inv = 1.0f / n;
    #pragma unroll
    for (int c = 0; c < 8; ++c) dst[((long)bg * HW_ + hw) * 8 + c] = v[c] * inv;
}

// ---------------------------------------------------------------------------
// Kernel 2: correlation volume  base[b,d,h,w,g] = inv * <fl(w), fr(w-d)>
// block = 256 threads = (g 0..7) x (wi 0..31); grid = (W/32, H, B)
// ---------------------------------------------------------------------------
__global__ __launch_bounds__(256) void corr_kernel(const float* __restrict__ fln,
                                                   const float* __restrict__ frn,
                                                   float* __restrict__ base) {
    int tid = threadIdx.x;
    int g = tid & 7, wi = tid >> 3;
    int w = blockIdx.x * 32 + wi;
    int h = blockIdx.y;
    int b = blockIdx.z;
    const float* flp  = fln + (size_t)((((b * G_ + g) * H_ + h) * W_ + w)) * 8;
    const float* frow = frn + (size_t)((((b * G_ + g) * H_ + h) * W_)) * 8;
    float4 a0 = *(const float4*)(flp);
    float4 a1 = *(const float4*)(flp + 4);
    const float inv = 0.35355339059327373f;  // 1/sqrt(8)
    for (int d = 0; d < D_; ++d) {
        int wd = w - d;
        float acc = 0.f;
        if (wd >= 0) {
            float4 b0 = *(const float4*)(frow + wd * 8);
            float4 b1 = *(const float4*)(frow + wd * 8 + 4);
            acc = a0.x * b0.x + a0.y * b0.y + a0.z * b0.z + a0.w * b0.w
                + a1.x * b1.x + a1.y * b1.y + a1.z * b1.z + a1.w * b1.w;
            acc *= inv;
        }
        base[(size_t)(((b * D_ + d) * H_ + h) * W_ + w) * 8 + g] = acc;
    }
}

// ---------------------------------------------------------------------------
// Kernel 3: 2D conv(65->32,3x3) + BN + relu + 1x1(32->3) + softmax -> sw
// one thread per pixel; weights via uniform (scalar) loads from wp1T
// ---------------------------------------------------------------------------
__global__ __launch_bounds__(256) void pred_kernel(const float* __restrict__ feat_l,
                                                   const float* __restrict__ edge,
                                                   const float* __restrict__ wp1T,
                                                   const float* __restrict__ gamma,
                                                   const float* __restrict__ beta,
                                                   const float* __restrict__ mean,
                                                   const float* __restrict__ var,
                                                   const float* __restrict__ w2,
                                                   const float* __restrict__ b2,
                                                   const float* __restrict__ temp,
                                                   float* __restrict__ sw) {
    int pid = blockIdx.x * 256 + threadIdx.x;   // 0..36863
    int b = pid / HW_; int hw = pid - b * HW_;
    int h = hw / W_;   int w = hw - h * W_;

    float acc[32];
    #pragma unroll
    for (int i = 0; i < 32; ++i) acc[i] = 0.f;

    for (int ic = 0; ic < 65; ++ic) {
        const float* src = (ic < 64) ? (feat_l + (size_t)(b * 64 + ic) * HW_)
                                     : (edge + (size_t)b * HW_);
        float v[9];
        #pragma unroll
        for (int ky = 0; ky < 3; ++ky) {
            int y = h + ky - 1;
            #pragma unroll
            for (int kx = 0; kx < 3; ++kx) {
                int x = w + kx - 1;
                bool ok = (y >= 0) && (y < H_) && (x >= 0) && (x < W_);
                v[ky * 3 + kx] = ok ? src[y * W_ + x] : 0.f;
            }
        }
        #pragma unroll
        for (int t = 0; t < 9; ++t) {
            const float* wrow = wp1T + (ic * 9 + t) * 32;
            float vv = v[t];
            #pragma unroll
            for (int oc = 0; oc < 32; ++oc) acc[oc] = fmaf(vv, wrow[oc], acc[oc]);
        }
    }

    float l0 = b2[0], l1 = b2[1], l2 = b2[2];
    #pragma unroll
    for (int oc = 0; oc < 32; ++oc) {
        float sc = gamma[oc] / sqrtf(var[oc] + 1e-5f);
        float xb = (acc[oc] - mean[oc]) * sc + beta[oc];
        float r = fmaxf(xb, 0.f);
        l0 = fmaf(w2[0 * 32 + oc], r, l0);
        l1 = fmaf(w2[1 * 32 + oc], r, l1);
        l2 = fmaf(w2[2 * 32 + oc], r, l2);
    }
    float t = fmaxf(temp[0], 0.1f);
    float it = 1.0f / t;
    l0 *= it; l1 *= it; l2 *= it;
    float m = fmaxf(l0, fmaxf(l1, l2));
    float e0 = expf(l0 - m), e1 = expf(l1 - m), e2 = expf(l2 - m);
    float is = 1.0f / (e0 + e1 + e2);
    sw[pid * 3 + 0] = e0 * is;
    sw[pid * 3 + 1] = e1 * is;
    sw[pid * 3 + 2] = e2 * is;
}

// ---------------------------------------------------------------------------
// Kernel 4: 3x dilated 3x3x3 conv (8->8) + softmax blend + 1x1x1 (8->32)
// thread = one (b,d,h,w); block 256 = (wi 0..63, hi 0..3)
// grid = (W/64, H/4, B*D)
// ---------------------------------------------------------------------------
__global__ __launch_bounds__(256) void fusedconv_kernel(const float* __restrict__ base,
                                                        const float* __restrict__ sw,
                                                        const float* __restrict__ wT,
                                                        const float* __restrict__ wf,
                                                        const float* __restrict__ bf,
                                                        float* __restrict__ out) {
    int tid = threadIdx.x;
    int wi = tid & 63, hi = tid >> 6;
    int w = blockIdx.x * 64 + wi;
    int h = blockIdx.y * 4 + hi;
    int bz = blockIdx.z; int b = bz / D_; int d = bz - b * D_;

    const float* swp = sw + ((size_t)b * HW_ + h * W_ + w) * 3;
    float swk0 = swp[0], swk1 = swp[1], swk2 = swp[2];

    float fused[8];
    #pragma unroll
    for (int g = 0; g < 8; ++g) fused[g] = 0.f;

    const int cbase = (((b * D_ + d) * H_ + h) * W_ + w) * 8;

    for (int k = 0; k < 3; ++k) {
        int dil = 1 << k;
        const float* wk = wT + k * 1728;
        float acc[8];
        #pragma unroll
        for (int g = 0; g < 8; ++g) acc[g] = 0.f;

        for (int tap = 0; tap < 27; ++tap) {
            int kd = tap / 9; int rem = tap - kd * 9;
            int kh = rem / 3; int kw = rem - kh * 3;
            int dd = d + (kd - 1) * dil;          // block-uniform
            int hh = h + (kh - 1) * dil;          // wave-uniform
            if (dd < 0 || dd >= D_ || hh < 0 || hh >= H_) continue;
            int ww = w + (kw - 1) * dil;          // per-lane
            bool ok = (ww >= 0) && (ww < W_);
            int idx = cbase + (((kd - 1) * dil * H_ + (kh - 1) * dil) * W_ + (kw - 1) * dil) * 8;
            float4 p0 = ok ? *(const float4*)(base + idx)     : make_float4(0.f, 0.f, 0.f, 0.f);
            float4 p1 = ok ? *(const float4*)(base + idx + 4) : make_float4(0.f, 0.f, 0.f, 0.f);
            float pv[8] = {p0.x, p0.y, p0.z, p0.w, p1.x, p1.y, p1.z, p1.w};
            const float* wt = wk + tap * 64;      // uniform -> SGPR loads
            #pragma unroll
            for (int gi = 0; gi < 8; ++gi) {
                float bv = pv[gi];
                #pragma unroll
                for (int g = 0; g < 8; ++g) acc[g] = fmaf(bv, wt[gi * 8 + g], acc[g]);
            }
        }
        float s = (k == 0) ? swk0 : (k == 1) ? swk1 : swk2;
        #pragma unroll
        for (int g = 0; g < 8; ++g) fused[g] = fmaf(s, acc[g], fused[g]);
    }

    // epilogue: 1x1x1 conv 8 -> 32 (+bias), NCDHW output
    int obase = (b * OUT_ * D_ + d) * HW_ + h * W_ + w;
    #pragma unroll
    for (int o = 0; o < OUT_; ++o) {
        float r = bf[o];
        #pragma unroll
        for (int g = 0; g < 8; ++g) r = fmaf(wf[o * 8 + g], fused[g], r);
        out[obase + o * (D_ * HW_)] = r;
    }
}

// ---------------------------------------------------------------------------
extern "C" void kernel_launch(void* const* d_in, const int* in_sizes, int n_in,
                              void* d_out, int out_size, void* d_ws, size_t ws_size,
                              hipStream_t stream) {
    const float* feat_l   = (const float*)d_in[0];
    const float* feat_r   = (const float*)d_in[1];
    const float* edge     = (const float*)d_in[2];
    const float* w_pred1  = (const float*)d_in[3];
    const float* bn_gamma = (const float*)d_in[4];
    const float* bn_beta  = (const float*)d_in[5];
    const float* bn_mean  = (const float*)d_in[6];
    const float* bn_var   = (const float*)d_in[7];
    const float* w_pred2  = (const float*)d_in[8];
    const float* b_pred2  = (const float*)d_in[9];
    const float* temp     = (const float*)d_in[10];
    const float* w_s      = (const float*)d_in[11];
    const float* w_m      = (const float*)d_in[12];
    const float* w_l      = (const float*)d_in[13];
    const float* w_final  = (const float*)d_in[14];
    const float* b_final  = (const float*)d_in[15];
    float* out = (float*)d_out;

    float* ws   = (float*)d_ws;
    float* fln  = ws + OFF_FLN;
    float* frn  = ws + OFF_FRN;
    float* base = ws + OFF_BASE;
    float* swb  = ws + OFF_SW;
    float* wT   = ws + OFF_WT;
    float* wp1T = ws + OFF_WP1T;

    // 0: weight transposes
    wtrans_kernel<<<dim3(94), 256, 0, stream>>>(w_s, w_m, w_l, w_pred1, wT, wp1T);
    // 1: normalize
    norm_kernel<<<dim3(HW_ / 256, B_ * G_, 2), 256, 0, stream>>>(feat_l, feat_r, fln, frn);
    // 2: correlation volume
    corr_kernel<<<dim3(W_ / 32, H_, B_), 256, 0, stream>>>(fln, frn, base);
    // 3: pred path -> softmax weights
    pred_kernel<<<dim3(B_ * HW_ / 256), 256, 0, stream>>>(feat_l, edge, wp1T, bn_gamma,
                                                          bn_beta, bn_mean, bn_var,
                                                          w_pred2, b_pred2, temp, swb);
    // 4: fused dilated convs + blend + expand
    fusedconv_kernel<<<dim3(W_ / 64, H_ / 4, B_ * D_), 256, 0, stream>>>(base, swb, wT,
                                                                         w_final, b_final, out);
}